// Round 1
// baseline (166.325 us; speedup 1.0000x reference)
//
#include <hip/hip_runtime.h>

// Problem constants (fixed by setup_inputs):
//   xyz (B,N,3) f32, new_xyz (B,P,3) f32, features (B,C,N) f32
//   out = concat([grouped_xyz - center, grouped_features], ch) -> (B, 3+C, P, S) f32
#define BB 2
#define NN 16384
#define PP 4096
#define CC 64
#define SS 32
#define R2 0.01f
#define OUTCH (3 + CC)

// ---------------------------------------------------------------------------
// Kernel 1: ball query. One 64-lane wave per query point.
// Scans xyz in chunks of 64; ballot -> ordered insertion of first 32 in-ball
// indices (ascending original index, matching PointNet++/reference top_k
// semantics). Pads trailing slots with the first valid index (0 if none).
// fp contract OFF so d2 rounding matches numpy ((dx^2+dy^2)+dz^2, no FMA).
// ---------------------------------------------------------------------------
__global__ __launch_bounds__(256) void ball_query_kernel(
    const float* __restrict__ xyz, const float* __restrict__ new_xyz,
    int* __restrict__ idx_out) {
#pragma clang fp contract(off)
  const int wave = blockIdx.x * (blockDim.x >> 6) + (threadIdx.x >> 6);
  const int lane = threadIdx.x & 63;
  if (wave >= BB * PP) return;
  const int b = wave >> 12;  // PP = 4096 = 2^12

  const float cx = new_xyz[wave * 3 + 0];
  const float cy = new_xyz[wave * 3 + 1];
  const float cz = new_xyz[wave * 3 + 2];
  const float* __restrict__ xb = xyz + (size_t)b * NN * 3;

  int cnt = 0;
  int firstIdx = 0;
  bool haveFirst = false;

  for (int base = 0; base < NN; base += 64) {
    const int i = base + lane;
    const float x = xb[i * 3 + 0];
    const float y = xb[i * 3 + 1];
    const float z = xb[i * 3 + 2];
    const float dx = cx - x;
    const float dy = cy - y;
    const float dz = cz - z;
    float d2 = dx * dx + dy * dy;
    d2 = d2 + dz * dz;
    const bool inball = d2 < R2;
    const unsigned long long mask = __ballot(inball);
    if (!haveFirst && mask != 0ull) {
      firstIdx = base + __builtin_ctzll(mask);
      haveFirst = true;
    }
    if (inball) {
      const int rank = (int)__popcll(mask & ((1ull << lane) - 1ull));
      const int slot = cnt + rank;
      if (slot < SS) idx_out[wave * SS + slot] = i;
    }
    cnt += (int)__popcll(mask);
    if (cnt >= SS) break;  // wave-uniform early exit
  }

  // Pad slots [cnt, 32) with first valid index (0 if none found).
  for (int s = cnt + lane; s < SS; s += 64) idx_out[wave * SS + s] = firstIdx;
}

// ---------------------------------------------------------------------------
// Kernel 2: gather + group. One thread per (b,p,s); idx held in a register
// and reused across all 67 output channels. For a fixed channel iteration,
// consecutive lanes -> consecutive (p,s) -> fully coalesced stores.
// Feature gathers are random within a 64KB row -> L1/L2 resident.
// ---------------------------------------------------------------------------
__global__ __launch_bounds__(256) void group_kernel(
    const float* __restrict__ xyz, const float* __restrict__ new_xyz,
    const float* __restrict__ feat, const int* __restrict__ idx,
    float* __restrict__ out) {
  const int t = blockIdx.x * blockDim.x + threadIdx.x;
  if (t >= BB * PP * SS) return;
  const int p = (t >> 5) & (PP - 1);
  const int b = t >> 17;  // PP*SS = 2^17 per batch
  const int v = idx[t];

  const float* __restrict__ xr = xyz + ((size_t)b * NN + v) * 3;
  const float* __restrict__ cr = new_xyz + (size_t)(b * PP + p) * 3;

  const size_t PS = (size_t)PP * SS;
  const size_t ob = (size_t)b * OUTCH * PS + ((size_t)t & (PS - 1));
  out[ob + 0 * PS] = xr[0] - cr[0];
  out[ob + 1 * PS] = xr[1] - cr[1];
  out[ob + 2 * PS] = xr[2] - cr[2];

  const float* __restrict__ fb = feat + (size_t)b * CC * NN + v;
  float* __restrict__ og = out + ob + 3 * PS;
#pragma unroll 8
  for (int c = 0; c < CC; ++c) {
    og[(size_t)c * PS] = fb[(size_t)c * NN];
  }
}

extern "C" void kernel_launch(void* const* d_in, const int* in_sizes, int n_in,
                              void* d_out, int out_size, void* d_ws, size_t ws_size,
                              hipStream_t stream) {
  const float* xyz = (const float*)d_in[0];
  const float* new_xyz = (const float*)d_in[1];
  const float* feat = (const float*)d_in[2];
  float* out = (float*)d_out;
  int* idx = (int*)d_ws;  // B*P*S ints = 1 MB scratch

  // Ball query: 8192 waves, 4 waves (256 threads) per block.
  const int nwaves = BB * PP;
  ball_query_kernel<<<nwaves / 4, 256, 0, stream>>>(xyz, new_xyz, idx);

  // Gather: one thread per (b,p,s).
  const int nthreads = BB * PP * SS;
  group_kernel<<<nthreads / 256, 256, 0, stream>>>(xyz, new_xyz, feat, idx, out);
}

// Round 2
// 81.903 us; speedup vs baseline: 2.0308x; 2.0308x over previous
//
#include <hip/hip_runtime.h>
#include <limits.h>

// Problem constants (fixed by setup_inputs):
//   xyz (B,N,3) f32, new_xyz (B,P,3) f32, features (B,C,N) f32
//   out = concat([grouped_xyz - center, grouped_features], ch) -> (B, 3+C, P, S) f32
#define BB 2
#define NN 16384
#define PP 4096
#define CC 64
#define SS 32
#define R2 0.01f
#define OUTCH (3 + CC)

// ---------------------------------------------------------------------------
// Kernel 1: ball query v2. One 64-lane wave per query point.
// Each lane handles 4 consecutive points per iteration (3x float4 = 48B,
// 16B-aligned since point index is a multiple of 4). 256 points/wave-iter.
// Ordered slot assignment via wave prefix scan of per-lane in-ball counts.
// Pads trailing slots with the first (minimum-index) in-ball point, 0 if none.
// fp contract OFF so d2 rounding matches numpy ((dx^2+dy^2)+dz^2, no FMA).
// ---------------------------------------------------------------------------
__global__ __launch_bounds__(256) void ball_query_kernel(
    const float* __restrict__ xyz, const float* __restrict__ new_xyz,
    int* __restrict__ idx_out) {
#pragma clang fp contract(off)
  const int wave = blockIdx.x * 4 + (threadIdx.x >> 6);
  const int lane = threadIdx.x & 63;
  const int b = wave >> 12;  // PP = 4096

  const float cx = new_xyz[wave * 3 + 0];
  const float cy = new_xyz[wave * 3 + 1];
  const float cz = new_xyz[wave * 3 + 2];
  const float4* __restrict__ xb4 = (const float4*)(xyz + (size_t)b * NN * 3);

  int cnt = 0;
  int firstCand = INT_MAX;  // running min in-ball index seen by this lane

  for (int chunk = 0; chunk < NN; chunk += 256) {
    const int q0 = chunk + 4 * lane;  // first of this lane's 4 points
    const float4* pf = xb4 + 3 * (size_t)(q0 >> 2);
    const float4 f0 = pf[0];
    const float4 f1 = pf[1];
    const float4 f2 = pf[2];

    float dx, dy, dz, a, d2;
    int m = 0;
    dx = cx - f0.x; dy = cy - f0.y; dz = cz - f0.z;
    a = dx * dx + dy * dy; d2 = a + dz * dz; m |= (d2 < R2) ? 1 : 0;
    dx = cx - f0.w; dy = cy - f1.x; dz = cz - f1.y;
    a = dx * dx + dy * dy; d2 = a + dz * dz; m |= (d2 < R2) ? 2 : 0;
    dx = cx - f1.z; dy = cy - f1.w; dz = cz - f2.x;
    a = dx * dx + dy * dy; d2 = a + dz * dz; m |= (d2 < R2) ? 4 : 0;
    dx = cx - f2.y; dy = cy - f2.z; dz = cz - f2.w;
    a = dx * dx + dy * dy; d2 = a + dz * dz; m |= (d2 < R2) ? 8 : 0;

    const int c = __popc(m);

    // inclusive prefix scan of c over lanes
    int incl = c;
#pragma unroll
    for (int d = 1; d < 64; d <<= 1) {
      int t = __shfl_up(incl, d);
      if (lane >= d) incl += t;
    }
    const int excl = incl - c;
    const int total = __shfl(incl, 63);

    if (m) {
      firstCand = min(firstCand, q0 + __builtin_ctz(m));
      int s = cnt + excl;
#pragma unroll
      for (int j = 0; j < 4; ++j) {
        if ((m >> j) & 1) {
          if (s < SS) idx_out[wave * SS + s] = q0 + j;
          ++s;
        }
      }
    }

    cnt += total;              // uniform across lanes
    if (cnt >= SS) break;      // wave-uniform early exit
  }

  // first in-ball index overall = wave-min of firstCand
  int fc = firstCand;
#pragma unroll
  for (int d = 32; d; d >>= 1) fc = min(fc, __shfl_xor(fc, d));
  if (fc == INT_MAX) fc = 0;

  for (int s = cnt + lane; s < SS; s += 64) idx_out[wave * SS + s] = fc;
}

// ---------------------------------------------------------------------------
// Kernel 2: transpose features (B,C,N) -> (B,N,C) so gathers read full
// contiguous 256B rows. 64x64 tiles, LDS padded +1.
// ---------------------------------------------------------------------------
__global__ __launch_bounds__(256) void transpose_feat_kernel(
    const float* __restrict__ feat, float* __restrict__ featT) {
  __shared__ float tile[64][65];
  const int n0 = blockIdx.x * 64;
  const int b = blockIdx.y;
  const int jn = threadIdx.x & 63;
  const int g4 = threadIdx.x >> 6;  // 0..3

  const float* fb = feat + (size_t)b * CC * NN;
#pragma unroll
  for (int k = 0; k < 16; ++k) {
    const int c = g4 * 16 + k;
    tile[c][jn] = fb[(size_t)c * NN + n0 + jn];
  }
  __syncthreads();
  float* ft = featT + ((size_t)b * NN + n0) * CC;
#pragma unroll
  for (int k = 0; k < 16; ++k) {
    const int j = g4 * 16 + k;
    ft[(size_t)j * CC + jn] = tile[jn][j];
  }
}

// ---------------------------------------------------------------------------
// Kernel 3: gather + group via LDS staging. Block = 256 threads handles
// TILE=128 samples. Phase 1: gather 128 full featT rows (256B contiguous
// each) into LDS (row stride 65 -> conflict-free). Phase 2: xyz channels.
// Phase 3: channel-major coalesced stores from LDS.
// ---------------------------------------------------------------------------
#define TILE 128
__global__ __launch_bounds__(256) void group_kernel_t(
    const float* __restrict__ xyz, const float* __restrict__ new_xyz,
    const float* __restrict__ featT, const int* __restrict__ idx,
    float* __restrict__ out) {
  __shared__ float lds[TILE * 65];
  const int base = blockIdx.x * TILE;  // sample base in [0, B*P*S)
  const int b = base >> 17;            // P*S = 2^17
  const int t = threadIdx.x;
  const size_t PS = (size_t)PP * SS;

  // phase 1: stage rows
  const float4* ftb = (const float4*)(featT + (size_t)b * NN * CC);
#pragma unroll
  for (int k = 0; k < 8; ++k) {
    const int u = k * 256 + t;     // [0, 2048)
    const int r = u >> 4;          // row 0..127
    const int q = u & 15;          // float4 within row
    const int v = idx[base + r];
    const float4 val = ftb[(size_t)v * 16 + q];
    float* dst = &lds[r * 65 + q * 4];
    dst[0] = val.x; dst[1] = val.y; dst[2] = val.z; dst[3] = val.w;
  }
  __syncthreads();

  // phase 2: xyz channels (one thread per sample, threads 0..127)
  if (t < TILE) {
    const int g = base + t;
    const int v = idx[g];
    const int p = (g >> 5) & (PP - 1);
    const float* xr = xyz + ((size_t)b * NN + v) * 3;
    const float* cr = new_xyz + (size_t)(b * PP + p) * 3;
    const size_t ob = (size_t)b * OUTCH * PS + ((size_t)g & (PS - 1));
    out[ob + 0 * PS] = xr[0] - cr[0];
    out[ob + 1 * PS] = xr[1] - cr[1];
    out[ob + 2 * PS] = xr[2] - cr[2];
  }

  // phase 3: feature stores, channel-major coalesced
  float* ob3 = out + (size_t)b * OUTCH * PS + 3 * PS + ((size_t)base & (PS - 1));
#pragma unroll
  for (int k = 0; k < 32; ++k) {
    const int u = k * 256 + t;   // [0, 8192)
    const int c = u >> 7;        // channel 0..63
    const int r = u & 127;       // row 0..127
    ob3[(size_t)c * PS + r] = lds[r * 65 + c];
  }
}

// ---------------------------------------------------------------------------
// Fallback group kernel (no transpose) if workspace is too small.
// ---------------------------------------------------------------------------
__global__ __launch_bounds__(256) void group_kernel(
    const float* __restrict__ xyz, const float* __restrict__ new_xyz,
    const float* __restrict__ feat, const int* __restrict__ idx,
    float* __restrict__ out) {
  const int t = blockIdx.x * blockDim.x + threadIdx.x;
  if (t >= BB * PP * SS) return;
  const int p = (t >> 5) & (PP - 1);
  const int b = t >> 17;
  const int v = idx[t];

  const float* xr = xyz + ((size_t)b * NN + v) * 3;
  const float* cr = new_xyz + (size_t)(b * PP + p) * 3;

  const size_t PS = (size_t)PP * SS;
  const size_t ob = (size_t)b * OUTCH * PS + ((size_t)t & (PS - 1));
  out[ob + 0 * PS] = xr[0] - cr[0];
  out[ob + 1 * PS] = xr[1] - cr[1];
  out[ob + 2 * PS] = xr[2] - cr[2];

  const float* fb = feat + (size_t)b * CC * NN + v;
  float* og = out + ob + 3 * PS;
#pragma unroll 8
  for (int c = 0; c < CC; ++c) {
    og[(size_t)c * PS] = fb[(size_t)c * NN];
  }
}

extern "C" void kernel_launch(void* const* d_in, const int* in_sizes, int n_in,
                              void* d_out, int out_size, void* d_ws, size_t ws_size,
                              hipStream_t stream) {
  const float* xyz = (const float*)d_in[0];
  const float* new_xyz = (const float*)d_in[1];
  const float* feat = (const float*)d_in[2];
  float* out = (float*)d_out;

  int* idx = (int*)d_ws;  // B*P*S ints = 1 MB
  const size_t idxBytes = (size_t)BB * PP * SS * sizeof(int);
  const size_t featTBytes = (size_t)BB * NN * CC * sizeof(float);  // 8.39 MB
  float* featT = (float*)((char*)d_ws + idxBytes);

  // Ball query: 8192 waves, 4 waves per block.
  ball_query_kernel<<<(BB * PP) / 4, 256, 0, stream>>>(xyz, new_xyz, idx);

  if (ws_size >= idxBytes + featTBytes) {
    transpose_feat_kernel<<<dim3(NN / 64, BB), 256, 0, stream>>>(feat, featT);
    group_kernel_t<<<(BB * PP * SS) / TILE, 256, 0, stream>>>(xyz, new_xyz, featT,
                                                              idx, out);
  } else {
    group_kernel<<<(BB * PP * SS) / 256, 256, 0, stream>>>(xyz, new_xyz, feat,
                                                           idx, out);
  }
}

// Round 3
// 71.497 us; speedup vs baseline: 2.3263x; 1.1455x over previous
//
#include <hip/hip_runtime.h>
#include <limits.h>

// Problem constants (fixed by setup_inputs):
//   xyz (B,N,3) f32, new_xyz (B,P,3) f32, features (B,C,N) f32
//   out = concat([grouped_xyz - center, grouped_features], ch) -> (B, 3+C, P, S) f32
#define BB 2
#define NN 16384
#define PP 4096
#define CC 64
#define SS 32
#define R2 0.01f
#define OUTCH (3 + CC)

// ---------------------------------------------------------------------------
// Kernel 1: ball query v3. One 64-lane wave per query point.
// 4 consecutive points per lane via 3x float4 coalesced loads (256 pts/iter).
// Ordered slot assignment WITHOUT a serial prefix scan:
//   4 ballots b0..b3 (bit l of bj = point 4l+j in-ball);
//   rank(l,j) = sum_j' popcll(bj' & below(l)) + popc(m & ((1<<j)-1))
// (lexicographic (lane, j) order == ascending point index). Chunk totals and
// the early-exit counter are wave-uniform (scalar pipe).
// fp contract OFF so d2 rounding matches numpy ((dx^2+dy^2)+dz^2, no FMA).
// ---------------------------------------------------------------------------
__global__ __launch_bounds__(256) void ball_query_kernel(
    const float* __restrict__ xyz, const float* __restrict__ new_xyz,
    int* __restrict__ idx_out) {
#pragma clang fp contract(off)
  const int wave = blockIdx.x * 4 + (threadIdx.x >> 6);
  const int lane = threadIdx.x & 63;
  const int b = wave >> 12;  // PP = 4096

  const float cx = new_xyz[wave * 3 + 0];
  const float cy = new_xyz[wave * 3 + 1];
  const float cz = new_xyz[wave * 3 + 2];
  const float4* __restrict__ xb4 = (const float4*)(xyz + (size_t)b * NN * 3);
  int* __restrict__ myout = idx_out + wave * SS;

  const unsigned long long below = (1ull << lane) - 1ull;

  int cnt = 0;
  int firstCand = INT_MAX;  // running min in-ball index seen by this lane

  for (int chunk = 0; chunk < NN; chunk += 256) {
    const int q0 = chunk + 4 * lane;  // first of this lane's 4 points
    const float4* pf = xb4 + 3 * (size_t)(q0 >> 2);
    const float4 f0 = pf[0];
    const float4 f1 = pf[1];
    const float4 f2 = pf[2];

    float dx, dy, dz, a, d2;
    dx = cx - f0.x; dy = cy - f0.y; dz = cz - f0.z;
    a = dx * dx + dy * dy; d2 = a + dz * dz;
    const bool c0 = d2 < R2;
    dx = cx - f0.w; dy = cy - f1.x; dz = cz - f1.y;
    a = dx * dx + dy * dy; d2 = a + dz * dz;
    const bool c1 = d2 < R2;
    dx = cx - f1.z; dy = cy - f1.w; dz = cz - f2.x;
    a = dx * dx + dy * dy; d2 = a + dz * dz;
    const bool c2 = d2 < R2;
    dx = cx - f2.y; dy = cy - f2.z; dz = cz - f2.w;
    a = dx * dx + dy * dy; d2 = a + dz * dz;
    const bool c3 = d2 < R2;

    const unsigned long long b0 = __ballot(c0);
    const unsigned long long b1 = __ballot(c1);
    const unsigned long long b2 = __ballot(c2);
    const unsigned long long b3 = __ballot(c3);

    const int m = (c0 ? 1 : 0) | (c1 ? 2 : 0) | (c2 ? 4 : 0) | (c3 ? 8 : 0);

    if (m) {
      // in-ball points in lanes below this one (all j), straight-line VALU
      const int pre = (int)__popcll(b0 & below) + (int)__popcll(b1 & below) +
                      (int)__popcll(b2 & below) + (int)__popcll(b3 & below);
      firstCand = min(firstCand, q0 + __builtin_ctz(m));
      int s = cnt + pre;
      if (m & 1) { if (s < SS) myout[s] = q0 + 0; ++s; }
      if (m & 2) { if (s < SS) myout[s] = q0 + 1; ++s; }
      if (m & 4) { if (s < SS) myout[s] = q0 + 2; ++s; }
      if (m & 8) { if (s < SS) myout[s] = q0 + 3; }
    }

    // wave-uniform totals (scalar pipe) + uniform early exit
    cnt += (int)__popcll(b0) + (int)__popcll(b1) + (int)__popcll(b2) +
           (int)__popcll(b3);
    if (cnt >= SS) break;
  }

  // first in-ball index overall = wave-min of firstCand
  int fc = firstCand;
#pragma unroll
  for (int d = 32; d; d >>= 1) fc = min(fc, __shfl_xor(fc, d));
  if (fc == INT_MAX) fc = 0;

  for (int s = cnt + lane; s < SS; s += 64) myout[s] = fc;
}

// ---------------------------------------------------------------------------
// Kernel 2: transpose features (B,C,N) -> (B,N,C) so gathers read full
// contiguous 256B rows. 64x64 tiles, LDS padded +1.
// ---------------------------------------------------------------------------
__global__ __launch_bounds__(256) void transpose_feat_kernel(
    const float* __restrict__ feat, float* __restrict__ featT) {
  __shared__ float tile[64][65];
  const int n0 = blockIdx.x * 64;
  const int b = blockIdx.y;
  const int jn = threadIdx.x & 63;
  const int g4 = threadIdx.x >> 6;  // 0..3

  const float* fb = feat + (size_t)b * CC * NN;
#pragma unroll
  for (int k = 0; k < 16; ++k) {
    const int c = g4 * 16 + k;
    tile[c][jn] = fb[(size_t)c * NN + n0 + jn];
  }
  __syncthreads();
  float* ft = featT + ((size_t)b * NN + n0) * CC;
#pragma unroll
  for (int k = 0; k < 16; ++k) {
    const int j = g4 * 16 + k;
    ft[(size_t)j * CC + jn] = tile[jn][j];
  }
}

// ---------------------------------------------------------------------------
// Kernel 3: gather + group via LDS staging. Block = 256 threads handles
// TILE=128 samples. Phase 1: gather 128 full featT rows (256B contiguous
// each) into LDS (row stride 65 -> conflict-free). Phase 2: xyz channels.
// Phase 3: channel-major coalesced stores from LDS.
// ---------------------------------------------------------------------------
#define TILE 128
__global__ __launch_bounds__(256) void group_kernel_t(
    const float* __restrict__ xyz, const float* __restrict__ new_xyz,
    const float* __restrict__ featT, const int* __restrict__ idx,
    float* __restrict__ out) {
  __shared__ float lds[TILE * 65];
  const int base = blockIdx.x * TILE;  // sample base in [0, B*P*S)
  const int b = base >> 17;            // P*S = 2^17
  const int t = threadIdx.x;
  const size_t PS = (size_t)PP * SS;

  // phase 1: stage rows
  const float4* ftb = (const float4*)(featT + (size_t)b * NN * CC);
#pragma unroll
  for (int k = 0; k < 8; ++k) {
    const int u = k * 256 + t;     // [0, 2048)
    const int r = u >> 4;          // row 0..127
    const int q = u & 15;          // float4 within row
    const int v = idx[base + r];
    const float4 val = ftb[(size_t)v * 16 + q];
    float* dst = &lds[r * 65 + q * 4];
    dst[0] = val.x; dst[1] = val.y; dst[2] = val.z; dst[3] = val.w;
  }
  __syncthreads();

  // phase 2: xyz channels (one thread per sample, threads 0..127)
  if (t < TILE) {
    const int g = base + t;
    const int v = idx[g];
    const int p = (g >> 5) & (PP - 1);
    const float* xr = xyz + ((size_t)b * NN + v) * 3;
    const float* cr = new_xyz + (size_t)(b * PP + p) * 3;
    const size_t ob = (size_t)b * OUTCH * PS + ((size_t)g & (PS - 1));
    out[ob + 0 * PS] = xr[0] - cr[0];
    out[ob + 1 * PS] = xr[1] - cr[1];
    out[ob + 2 * PS] = xr[2] - cr[2];
  }

  // phase 3: feature stores, channel-major coalesced
  float* ob3 = out + (size_t)b * OUTCH * PS + 3 * PS + ((size_t)base & (PS - 1));
#pragma unroll
  for (int k = 0; k < 32; ++k) {
    const int u = k * 256 + t;   // [0, 8192)
    const int c = u >> 7;        // channel 0..63
    const int r = u & 127;       // row 0..127
    ob3[(size_t)c * PS + r] = lds[r * 65 + c];
  }
}

extern "C" void kernel_launch(void* const* d_in, const int* in_sizes, int n_in,
                              void* d_out, int out_size, void* d_ws, size_t ws_size,
                              hipStream_t stream) {
  const float* xyz = (const float*)d_in[0];
  const float* new_xyz = (const float*)d_in[1];
  const float* feat = (const float*)d_in[2];
  float* out = (float*)d_out;

  int* idx = (int*)d_ws;  // B*P*S ints = 1 MB
  const size_t idxBytes = (size_t)BB * PP * SS * sizeof(int);
  float* featT = (float*)((char*)d_ws + idxBytes);  // 8.39 MB

  // Ball query: 8192 waves, 4 waves per block.
  ball_query_kernel<<<(BB * PP) / 4, 256, 0, stream>>>(xyz, new_xyz, idx);

  transpose_feat_kernel<<<dim3(NN / 64, BB), 256, 0, stream>>>(feat, featT);
  group_kernel_t<<<(BB * PP * SS) / TILE, 256, 0, stream>>>(xyz, new_xyz, featT,
                                                            idx, out);
}

// Round 4
// 62.637 us; speedup vs baseline: 2.6554x; 1.1415x over previous
//
#include <hip/hip_runtime.h>
#include <limits.h>

// Problem constants (fixed by setup_inputs):
//   xyz (B,N,3) f32, new_xyz (B,P,3) f32, features (B,C,N) f32
//   out = concat([grouped_xyz - center, grouped_features], ch) -> (B, 3+C, P, S)
#define BB 2
#define NN 16384
#define PP 4096
#define CC 64
#define SS 32
#define R2 0.01f
#define OUTCH (3 + CC)
#define GRES 10
#define NCELL 1000  // 10x10x10, cell size 0.1 == radius

__device__ __forceinline__ int cell_of(float v) {
  int q = (int)(v * 10.0f);  // v in [0,1): floor
  return q < 0 ? 0 : (q > GRES - 1 ? GRES - 1 : q);
}
__device__ __forceinline__ int cell_clamp_floor(float v) {
  int q = (int)floorf(v * 10.0f);
  return q < 0 ? 0 : (q > GRES - 1 ? GRES - 1 : q);
}

// --------------------------------------------------------------------------
// Binning: zero counters -> histogram -> exclusive scan -> scatter to CSR.
// sorted4[pos] = (x, y, z, bitcast(orig_idx)). Within-cell order is atomic-
// arrival (nondeterministic) but the final output depends only on the SET of
// in-ball indices (bitmap), so results are deterministic.
// --------------------------------------------------------------------------
__global__ void zero_counters_kernel(int* hist, int* fill) {
  const int t = blockIdx.x * blockDim.x + threadIdx.x;
  if (t < BB * NCELL) { hist[t] = 0; fill[t] = 0; }
}

__global__ __launch_bounds__(256) void hist_kernel(const float* __restrict__ xyz,
                                                   int* __restrict__ hist) {
  const int i = blockIdx.x * 256 + threadIdx.x;  // 0 .. BB*NN
  const int b = i >> 14;
  const float* p = xyz + (size_t)i * 3;
  const int c = (cell_of(p[2]) * GRES + cell_of(p[1])) * GRES + cell_of(p[0]);
  atomicAdd(hist + b * NCELL + c, 1);
}

__global__ __launch_bounds__(1024) void scan_kernel(const int* __restrict__ hist,
                                                    int* __restrict__ cellStart) {
  __shared__ int sm[1024];
  const int b = blockIdx.x;
  const int t = threadIdx.x;
  const int own = (t < NCELL) ? hist[b * NCELL + t] : 0;
  sm[t] = own;
  __syncthreads();
  for (int off = 1; off < 1024; off <<= 1) {
    const int v = (t >= off) ? sm[t - off] : 0;
    __syncthreads();
    sm[t] += v;
    __syncthreads();
  }
  if (t < NCELL) cellStart[b * 1001 + t] = sm[t] - own;
  if (t == NCELL - 1) cellStart[b * 1001 + NCELL] = sm[t];
}

__global__ __launch_bounds__(256) void scatter_kernel(
    const float* __restrict__ xyz, const int* __restrict__ cellStart,
    int* __restrict__ fill, float4* __restrict__ sorted4) {
  const int i = blockIdx.x * 256 + threadIdx.x;
  const int b = i >> 14;
  const float* p = xyz + (size_t)i * 3;
  const float x = p[0], y = p[1], z = p[2];
  const int c = (cell_of(z) * GRES + cell_of(y)) * GRES + cell_of(x);
  const int r = atomicAdd(fill + b * NCELL + c, 1);
  const int pos = cellStart[b * 1001 + c] + r;
  float4 v;
  v.x = x; v.y = y; v.z = z; v.w = __int_as_float(i & (NN - 1));
  sorted4[(size_t)b * NN + pos] = v;
}

// --------------------------------------------------------------------------
// Ball query v4: one wave per query. Ball box spans <=3 cells/axis => 9
// contiguous CSR ranges (~450 candidates total, near-constant per query:
// no slow-wave tail). In-ball original indices marked in a per-wave 16384-bit
// LDS bitmap (padded 8+1 words per lane => conflict-free); one popcount +
// shfl-scan pass emits the first SS indices in ascending order.
// Box has +1e-5 margin: fp rounding can only ADD exactly-tested candidates.
// fp contract OFF so d2 matches numpy ((dx^2+dy^2)+dz^2, no FMA) bit-exact.
// --------------------------------------------------------------------------
__global__ __launch_bounds__(256) void ball_query_grid(
    const float4* __restrict__ sorted4, const int* __restrict__ cellStart,
    const float* __restrict__ new_xyz, int* __restrict__ idx_out) {
#pragma clang fp contract(off)
  __shared__ unsigned bmAll[4 * 576];  // 4 waves x (512 words padded to 64*9)
  const int widx = threadIdx.x >> 6;
  const int lane = threadIdx.x & 63;
  const int wave = blockIdx.x * 4 + widx;
  const int b = wave >> 12;  // PP = 4096
  unsigned* bm = bmAll + widx * 576;

  const float cx = new_xyz[wave * 3 + 0];
  const float cy = new_xyz[wave * 3 + 1];
  const float cz = new_xyz[wave * 3 + 2];
  const float4* __restrict__ sb = sorted4 + (size_t)b * NN;
  const int* __restrict__ csb = cellStart + b * 1001;
  int* __restrict__ myout = idx_out + wave * SS;

#pragma unroll
  for (int k = 0; k < 9; ++k) bm[k * 64 + lane] = 0;

  const float mg = 0.1f + 1e-5f;
  const int lox = cell_clamp_floor(cx - mg), hix = cell_clamp_floor(cx + mg);
  const int loy = cell_clamp_floor(cy - mg), hiy = cell_clamp_floor(cy + mg);
  const int loz = cell_clamp_floor(cz - mg), hiz = cell_clamp_floor(cz + mg);
  const int nx = hix - lox + 1;

  for (int zc = loz; zc <= hiz; ++zc) {
    for (int yc = loy; yc <= hiy; ++yc) {
      const int c0 = (zc * GRES + yc) * GRES + lox;
      int s0 = __builtin_amdgcn_readfirstlane(csb[c0]);
      int e0 = __builtin_amdgcn_readfirstlane(csb[c0 + nx]);
      for (int o = s0; o < e0; o += 64) {
        const int j = o + lane;
        if (j < e0) {
          const float4 pt = sb[j];
          const float dx = cx - pt.x;
          const float dy = cy - pt.y;
          const float dz = cz - pt.z;
          const float a = dx * dx + dy * dy;
          const float d2 = a + dz * dz;
          if (d2 < R2) {
            const int orig = __float_as_int(pt.w);
            const int wi = orig >> 5;  // word 0..511
            atomicOr(&bm[(wi >> 3) * 9 + (wi & 7)], 1u << (orig & 31));
          }
        }
      }
    }
  }
  __threadfence_block();  // drain LDS atomics before the scan reads

  // Scan: lane l owns words [8l,8l+8) = orig indices [256l, 256l+256).
  unsigned w[8];
  int c = 0;
  int fi = INT_MAX;
#pragma unroll
  for (int k = 0; k < 8; ++k) {
    w[k] = bm[lane * 9 + k];
    c += (int)__popc(w[k]);
    if (fi == INT_MAX && w[k]) fi = lane * 256 + k * 32 + (int)__builtin_ctz(w[k]);
  }

  int incl = c;
#pragma unroll
  for (int d = 1; d < 64; d <<= 1) {
    const int t = __shfl_up(incl, d);
    if (lane >= d) incl += t;
  }
  const int E = incl - c;               // exclusive prefix
  const int total = __shfl(incl, 63);   // wave total in-ball count

  const unsigned long long nb = __ballot(c > 0);
  int fc = 0;
  if (nb) fc = __shfl(fi, (int)__builtin_ctzll(nb));

  int s = E;
  if (s < SS) {
#pragma unroll
    for (int k = 0; k < 8; ++k) {
      unsigned ww = w[k];
      while (ww && s < SS) {
        const int bpos = (int)__builtin_ctz(ww);
        ww &= ww - 1;
        myout[s++] = lane * 256 + k * 32 + bpos;
      }
      if (s >= SS) break;
    }
  }
  for (int s2 = total + lane; s2 < SS; s2 += 64) myout[s2] = fc;
}

// --------------------------------------------------------------------------
// Transpose features (B,C,N) -> (B,N,C): gathers then read full 256B rows.
// --------------------------------------------------------------------------
__global__ __launch_bounds__(256) void transpose_feat_kernel(
    const float* __restrict__ feat, float* __restrict__ featT) {
  __shared__ float tile[64][65];
  const int n0 = blockIdx.x * 64;
  const int b = blockIdx.y;
  const int jn = threadIdx.x & 63;
  const int g4 = threadIdx.x >> 6;

  const float* fb = feat + (size_t)b * CC * NN;
#pragma unroll
  for (int k = 0; k < 16; ++k) {
    const int c = g4 * 16 + k;
    tile[c][jn] = fb[(size_t)c * NN + n0 + jn];
  }
  __syncthreads();
  float* ft = featT + ((size_t)b * NN + n0) * CC;
#pragma unroll
  for (int k = 0; k < 16; ++k) {
    const int j = g4 * 16 + k;
    ft[(size_t)j * CC + jn] = tile[jn][j];
  }
}

// --------------------------------------------------------------------------
// Gather + group via LDS staging (TILE=128 samples/block), coalesced stores.
// --------------------------------------------------------------------------
#define TILE 128
__global__ __launch_bounds__(256) void group_kernel_t(
    const float* __restrict__ xyz, const float* __restrict__ new_xyz,
    const float* __restrict__ featT, const int* __restrict__ idx,
    float* __restrict__ out) {
  __shared__ float lds[TILE * 65];
  const int base = blockIdx.x * TILE;
  const int b = base >> 17;  // P*S = 2^17
  const int t = threadIdx.x;
  const size_t PS = (size_t)PP * SS;

  const float4* ftb = (const float4*)(featT + (size_t)b * NN * CC);
#pragma unroll
  for (int k = 0; k < 8; ++k) {
    const int u = k * 256 + t;
    const int r = u >> 4;
    const int q = u & 15;
    const int v = idx[base + r];
    const float4 val = ftb[(size_t)v * 16 + q];
    float* dst = &lds[r * 65 + q * 4];
    dst[0] = val.x; dst[1] = val.y; dst[2] = val.z; dst[3] = val.w;
  }
  __syncthreads();

  if (t < TILE) {
    const int g = base + t;
    const int v = idx[g];
    const int p = (g >> 5) & (PP - 1);
    const float* xr = xyz + ((size_t)b * NN + v) * 3;
    const float* cr = new_xyz + (size_t)(b * PP + p) * 3;
    const size_t ob = (size_t)b * OUTCH * PS + ((size_t)g & (PS - 1));
    out[ob + 0 * PS] = xr[0] - cr[0];
    out[ob + 1 * PS] = xr[1] - cr[1];
    out[ob + 2 * PS] = xr[2] - cr[2];
  }

  float* ob3 = out + (size_t)b * OUTCH * PS + 3 * PS + ((size_t)base & (PS - 1));
#pragma unroll
  for (int k = 0; k < 32; ++k) {
    const int u = k * 256 + t;
    const int c = u >> 7;
    const int r = u & 127;
    ob3[(size_t)c * PS + r] = lds[r * 65 + c];
  }
}

extern "C" void kernel_launch(void* const* d_in, const int* in_sizes, int n_in,
                              void* d_out, int out_size, void* d_ws, size_t ws_size,
                              hipStream_t stream) {
  const float* xyz = (const float*)d_in[0];
  const float* new_xyz = (const float*)d_in[1];
  const float* feat = (const float*)d_in[2];
  float* out = (float*)d_out;

  // ws layout: [idx 1MB][featT 8.39MB]; the binning region ALIASES featT
  // (binning + ball query complete before transpose writes featT -- all
  // kernels are stream-serialized, so the overlap is dead by then).
  const size_t idxBytes = (size_t)BB * PP * SS * sizeof(int);
  int* idx = (int*)d_ws;
  char* ovl = (char*)d_ws + idxBytes;
  float* featT = (float*)ovl;
  float4* sorted4 = (float4*)ovl;                                   // 524288 B
  int* cellStart = (int*)(ovl + (size_t)BB * NN * sizeof(float4));  // 8008 B
  int* hist = cellStart + BB * 1001 + 2;                            // 8000 B
  int* fill = hist + BB * NCELL;                                    // 8000 B

  zero_counters_kernel<<<(BB * NCELL + 255) / 256, 256, 0, stream>>>(hist, fill);
  hist_kernel<<<(BB * NN) / 256, 256, 0, stream>>>(xyz, hist);
  scan_kernel<<<BB, 1024, 0, stream>>>(hist, cellStart);
  scatter_kernel<<<(BB * NN) / 256, 256, 0, stream>>>(xyz, cellStart, fill, sorted4);
  ball_query_grid<<<(BB * PP) / 4, 256, 0, stream>>>(sorted4, cellStart, new_xyz, idx);

  transpose_feat_kernel<<<dim3(NN / 64, BB), 256, 0, stream>>>(feat, featT);
  group_kernel_t<<<(BB * PP * SS) / TILE, 256, 0, stream>>>(xyz, new_xyz, featT,
                                                            idx, out);
}